// Round 3
// baseline (336.267 us; speedup 1.0000x reference)
//
#include <hip/hip_runtime.h>

// COO SpMM: out[r,:] = sum_e vals[e] * seq[cols[e],:], rows sorted.
// N=50000, E=1.25M, D=64, fp32.
//
// R1: lane=feature, 256B gathers, batch-8          -> 56.6 us (latency-bound)
// R2: deep double-buffer pipeline                  -> 66.5 us REGRESSED
//     (VGPR 24->60, VALUBusy down; depth didn't raise bytes-in-flight enough)
// R3: float4 gathers — 16 lanes x float4 = 64 features, 4 edges per gather
//     instruction (1 KB/instr). 4x payload per outstanding request, ~2.5x
//     less VALU per edge. Single-buffer batch-8 (R1 structure).

#define D_FEAT 64
#define EPW 128              // edges per wave
#define WAVES_PER_BLOCK 4    // 256-thread blocks

__global__ __launch_bounds__(256) void spmm_coo_kernel(
    const float* __restrict__ seq,   // [N, 64]
    const float* __restrict__ vals,  // [E]
    const int*   __restrict__ rows,  // [E] sorted
    const int*   __restrict__ cols,  // [E]
    float*       __restrict__ out,   // [N, 64], pre-zeroed
    int n_edges)
{
    const int lane = threadIdx.x & 63;
    const int wave = blockIdx.x * WAVES_PER_BLOCK + (threadIdx.x >> 6);

    const long long s_ll = (long long)wave * EPW;
    if (s_ll >= n_edges) return;
    const int s   = (int)s_ll;
    const int rem = n_edges - s;

    if (rem >= EPW) {
        // ---- fast path: full 128-edge chunk ----
        const int sub = lane >> 4;      // 0..3: which edge of each 4-edge group
        const int fq  = lane & 15;      // feature quad: features 4*fq .. 4*fq+3

        // metadata for 128 edges: 2 coalesced loads per array
        const int e0 = s + lane, e1 = s + 64 + lane;
        const int   r0 = rows[e0], r1 = rows[e1];
        const int   c0 = cols[e0], c1 = cols[e1];
        const float v0 = vals[e0], v1 = vals[e1];

        const float4* seq4 = (const float4*)seq;   // [N][16]
        float4 acc = make_float4(0.f, 0.f, 0.f, 0.f);
        int cur_row = __shfl(r0, sub);  // row of this lane's first edge

        // 32 steps of 4 edges; two halves of 64 edges; 2 batches of 8 steps each
#pragma unroll
        for (int half = 0; half < 2; ++half) {
            const int   rh = half ? r1 : r0;
            const int   ch = half ? c1 : c0;
            const float vh = half ? v1 : v0;
#pragma unroll
            for (int bb = 0; bb < 2; ++bb) {
                float4 x[8];
                // issue 8 independent 1KB gathers
#pragma unroll
                for (int u = 0; u < 8; ++u) {
                    const int j  = (bb * 8 + u) * 4 + sub;   // edge idx in half
                    const int cj = __shfl(ch, j);            // per-lane bpermute
                    x[u] = seq4[(long long)cj * 16 + fq];
                }
                // consume
#pragma unroll
                for (int u = 0; u < 8; ++u) {
                    const int   j  = (bb * 8 + u) * 4 + sub;
                    const int   rj = __shfl(rh, j);
                    const float vj = __shfl(vh, j);
                    if (__any(rj != cur_row)) {              // rare (~6/wave)
                        if (rj != cur_row) {
                            float* o = out + cur_row * D_FEAT + fq * 4;
                            atomicAdd(o + 0, acc.x);
                            atomicAdd(o + 1, acc.y);
                            atomicAdd(o + 2, acc.z);
                            atomicAdd(o + 3, acc.w);
                            acc = make_float4(0.f, 0.f, 0.f, 0.f);
                            cur_row = rj;
                        }
                    }
                    acc.x = fmaf(vj, x[u].x, acc.x);
                    acc.y = fmaf(vj, x[u].y, acc.y);
                    acc.z = fmaf(vj, x[u].z, acc.z);
                    acc.w = fmaf(vj, x[u].w, acc.w);
                }
            }
        }
        float* o = out + cur_row * D_FEAT + fq * 4;
        atomicAdd(o + 0, acc.x);
        atomicAdd(o + 1, acc.y);
        atomicAdd(o + 2, acc.z);
        atomicAdd(o + 3, acc.w);
    } else {
        // ---- tail: last wave only (<128 edges); scalar lane=feature path ----
        int   cur_row = rows[s];
        float acc     = 0.f;
        for (int j = 0; j < rem; ++j) {
            const int   e  = s + j;
            const int   rj = rows[e];   // uniform address -> broadcast
            const int   cj = cols[e];
            const float vj = vals[e];
            if (rj != cur_row) {
                atomicAdd(&out[cur_row * D_FEAT + lane], acc);
                cur_row = rj;
                acc = 0.f;
            }
            acc = fmaf(vj, seq[cj * D_FEAT + lane], acc);
        }
        atomicAdd(&out[cur_row * D_FEAT + lane], acc);
    }
}

extern "C" void kernel_launch(void* const* d_in, const int* in_sizes, int n_in,
                              void* d_out, int out_size, void* d_ws, size_t ws_size,
                              hipStream_t stream) {
    const float* seq  = (const float*)d_in[0];
    const float* vals = (const float*)d_in[1];
    const int*   rows = (const int*)d_in[2];
    const int*   cols = (const int*)d_in[3];
    float*       out  = (float*)d_out;

    const int n_edges = in_sizes[1];  // E

    // out is poisoned 0xAA before every timed call -> zero it every call
    hipMemsetAsync(d_out, 0, (size_t)out_size * sizeof(float), stream);

    const int waves  = (n_edges + EPW - 1) / EPW;
    const int blocks = (waves + WAVES_PER_BLOCK - 1) / WAVES_PER_BLOCK;
    spmm_coo_kernel<<<blocks, 256, 0, stream>>>(seq, vals, rows, cols, out, n_edges);
}

// Round 4
// 132.743 us; speedup vs baseline: 2.5332x; 2.5332x over previous
//
#include <hip/hip_runtime.h>

// COO SpMM: out[r,:] = sum_e vals[e] * seq[cols[e],:], rows sorted.
// N=50000, E=1.25M, D=64, fp32.
//
// R1: lane=feature, 256B gathers, batch-8, atomic flush  -> 56.6 us
// R2: deep double-buffer                                  -> 66.5 us FAIL
// R3: float4 gathers + interleaved streams + scalar atomics -> 270 us FAIL
//     (WRITE_SIZE 233 MB: 15M same-address dword atomics serialize at TCC)
// R4: float4 gathers (1 KB/instr, 4x bytes per outstanding request) + row
//     OWNERSHIP: each 16-lane sub-wave owns 2 rows exclusively -> plain
//     stores, zero atomics, no memset. row_start[] built by adjacent-diff
//     setup kernel (no binary search).

#define RPS 2               // rows per 16-lane sub-wave
#define RPW (4 * RPS)       // rows per wave
#define WPB 4               // waves per 256-thread block

// row_start[t] = first edge e with rows[e] >= t, for t in [0, n_nodes].
// Adjacent-diff: thread e fills targets (rows[e-1], rows[e]].
__global__ __launch_bounds__(256) void row_ptr_kernel(
    const int* __restrict__ rows, int* __restrict__ row_start,
    int n_edges, int n_nodes)
{
    const int e = blockIdx.x * blockDim.x + threadIdx.x;
    if (e >= n_edges) return;
    const int r    = rows[e];
    const int prev = (e == 0) ? -1 : rows[e - 1];
    for (int t = prev + 1; t <= r; ++t) row_start[t] = e;
    if (e == n_edges - 1)
        for (int t = r + 1; t <= n_nodes; ++t) row_start[t] = n_edges;
}

__global__ __launch_bounds__(256) void spmm_kernel(
    const float* __restrict__ seq,        // [N, 64]
    const float* __restrict__ vals,       // [E]
    const int*   __restrict__ rows,       // [E] sorted
    const int*   __restrict__ cols,       // [E]
    const int*   __restrict__ row_start,  // [N+1]
    float*       __restrict__ out,        // [N, 64]
    int n_nodes)
{
    const int lane = threadIdx.x & 63;
    const int sub  = lane >> 4;           // which 16-lane sub-wave
    const int fq   = lane & 15;           // feature quad: floats 4*fq..4*fq+3
    const int wave = blockIdx.x * WPB + (threadIdx.x >> 6);

    const int r0 = wave * RPW + sub * RPS;   // first owned row
    if (wave * RPW >= n_nodes) return;       // uniform for the whole wave

    int       e     = row_start[r0];         // 4 distinct addrs/wave: cheap
    const int e_end = row_start[r0 + RPS];

    const float4* seq4 = (const float4*)seq;
    float4*       out4 = (float4*)out;

    int    cur_row = r0;
    float4 acc     = make_float4(0.f, 0.f, 0.f, 0.f);

    while (__any(e < e_end)) {
        const int n = min(8, e_end - e);     // 0 for finished sub-waves

        // metadata for this sub-wave's next 8 edges (4 distinct dwords/wave
        // per load -> near-broadcast); issued before the gathers
        int   rr[8], cc[8];
        float vv[8];
#pragma unroll
        for (int u = 0; u < 8; ++u) {
            if (u < n) {
                rr[u] = rows[e + u];
                cc[u] = cols[e + u];
                vv[u] = vals[e + u];
            }
        }

        // 8 independent gathers; each instr moves 4 subs x 256 B = 1 KB
        float4 x[8];
#pragma unroll
        for (int u = 0; u < 8; ++u) {
            if (u < n) x[u] = seq4[cc[u] * 16 + fq];
        }

        // consume; row change -> plain store (exclusive ownership)
#pragma unroll
        for (int u = 0; u < 8; ++u) {
            if (u < n) {
                if (rr[u] != cur_row) {
                    out4[cur_row * 16 + fq] = acc;
                    for (int t = cur_row + 1; t < rr[u]; ++t)   // empty rows
                        out4[t * 16 + fq] = make_float4(0.f, 0.f, 0.f, 0.f);
                    cur_row = rr[u];
                    acc = make_float4(0.f, 0.f, 0.f, 0.f);
                }
                acc.x = fmaf(vv[u], x[u].x, acc.x);
                acc.y = fmaf(vv[u], x[u].y, acc.y);
                acc.z = fmaf(vv[u], x[u].z, acc.z);
                acc.w = fmaf(vv[u], x[u].w, acc.w);
            }
        }
        e += n;
    }

    // final flush + zero-fill the rest of the owned range (covers empty rows;
    // also writes zeros when the sub-range had no edges at all)
    const int r_hi = min(r0 + RPS, n_nodes);
    if (cur_row < r_hi) {
        out4[cur_row * 16 + fq] = acc;
        for (int t = cur_row + 1; t < r_hi; ++t)
            out4[t * 16 + fq] = make_float4(0.f, 0.f, 0.f, 0.f);
    }
}

extern "C" void kernel_launch(void* const* d_in, const int* in_sizes, int n_in,
                              void* d_out, int out_size, void* d_ws, size_t ws_size,
                              hipStream_t stream) {
    const float* seq  = (const float*)d_in[0];
    const float* vals = (const float*)d_in[1];
    const int*   rows = (const int*)d_in[2];
    const int*   cols = (const int*)d_in[3];
    float*       out  = (float*)d_out;

    const int n_edges = in_sizes[1];            // E
    const int n_nodes = out_size / 64;          // N (out is [1,N,64])

    int* row_start = (int*)d_ws;                // N+1 ints, rebuilt every call

    {
        const int threads = 256;
        const int blocks  = (n_edges + threads - 1) / threads;
        row_ptr_kernel<<<blocks, threads, 0, stream>>>(rows, row_start,
                                                       n_edges, n_nodes);
    }
    {
        const int waves  = (n_nodes + RPW - 1) / RPW;
        const int blocks = (waves + WPB - 1) / WPB;
        spmm_kernel<<<blocks, 256, 0, stream>>>(seq, vals, rows, cols,
                                                row_start, out, n_nodes);
    }
}

// Round 5
// 126.659 us; speedup vs baseline: 2.6549x; 1.0480x over previous
//
#include <hip/hip_runtime.h>

// COO SpMM: out[r,:] = sum_e vals[e] * seq[cols[e],:], rows sorted.
// N=50000, E=1.25M, D=64, fp32.
//
// R1: lane=feature, 256B gathers, atomic flush      -> 56.6 us
// R2: deep double-buffer                            -> 66.5 us FAIL
// R3: float4 + interleaved streams + dword atomics  -> 270 us FAIL (WRITE 233MB)
// R4: float4 + row ownership, scalar per-edge meta  -> 60 us (avg payload
//     268 B/request == R1's 256 B; request-cap equilibrium unchanged)
// R5: rows[] eliminated (row_start boundaries); metadata loaded coalesced
//     (2 x 256 B fully-useful per 64 edges) + bpermute broadcast; 16 x 1 KB
//     gathers in flight. Avg useful payload 939 B/request (3.7x R1).

#define RPS 2               // rows per 16-lane sub-wave (flush logic assumes 2)
#define RPW (4 * RPS)       // rows per wave
#define WPB 4               // waves per 256-thread block

// row_start[t] = first edge e with rows[e] >= t, t in [0, n_nodes].
__global__ __launch_bounds__(256) void row_ptr_kernel(
    const int* __restrict__ rows, int* __restrict__ row_start,
    int n_edges, int n_nodes)
{
    const int e = blockIdx.x * blockDim.x + threadIdx.x;
    if (e >= n_edges) return;
    const int r    = rows[e];
    const int prev = (e == 0) ? -1 : rows[e - 1];
    for (int t = prev + 1; t <= r; ++t) row_start[t] = e;
    if (e == n_edges - 1)
        for (int t = r + 1; t <= n_nodes; ++t) row_start[t] = n_edges;
}

__global__ __launch_bounds__(256) void spmm_kernel(
    const float* __restrict__ seq,        // [N, 64]
    const float* __restrict__ vals,       // [E]
    const int*   __restrict__ cols,       // [E]
    const int*   __restrict__ row_start,  // [N+1]
    float*       __restrict__ out,        // [N, 64]
    int n_nodes, int n_edges)
{
    const int lane = threadIdx.x & 63;
    const int sub  = lane >> 4;           // 16-lane sub-wave id (0..3)
    const int fl   = lane & 15;           // lane-in-sub == feature quad
    const int wave = blockIdx.x * WPB + (threadIdx.x >> 6);

    const int r0 = wave * RPW + sub * RPS;     // this sub's first owned row
    if (wave * RPW >= n_nodes) return;         // wave-uniform exit
    const bool sub_valid = (r0 < n_nodes);

    int e = 0, mid = 0, e_end = 0;
    if (sub_valid) {
        e     = row_start[r0];
        mid   = row_start[r0 + 1];             // boundary between owned rows
        e_end = row_start[min(r0 + RPS, n_nodes)];
    }

    const float4* seq4 = (const float4*)seq;   // [N][16]
    float4*       out4 = (float4*)out;

    int    cur_row = r0;
    float4 acc     = make_float4(0.f, 0.f, 0.f, 0.f);

    while (__any(e < e_end)) {
        // coalesced metadata: 16 consecutive edges per sub, 4 x 64 B
        // fully-useful segments per instruction
        int cidx = e + fl;
        cidx = (cidx < 0) ? 0 : (cidx >= n_edges ? n_edges - 1 : cidx);
        const int   c = cols[cidx];
        const float v = vals[cidx];

        // 16 independent gathers, 1 KB each (4 subs x 256 B row-slices)
        float4 x[16];
#pragma unroll
        for (int u = 0; u < 16; ++u) {
            const int cu = __shfl(c, (sub << 4) | u);   // sub-local broadcast
            x[u] = seq4[(cu << 4) + fl];                // safe even if inactive
        }

        // consume
#pragma unroll
        for (int u = 0; u < 16; ++u) {
            const int   eidx = e + u;
            const float vu   = __shfl(v, (sub << 4) | u);
            if (eidx < e_end) {
                if (eidx >= mid && cur_row == r0) {     // cross into 2nd row
                    out4[(cur_row << 4) + fl] = acc;    // exclusive: plain store
                    acc     = make_float4(0.f, 0.f, 0.f, 0.f);
                    cur_row = r0 + 1;
                }
                acc.x = fmaf(vu, x[u].x, acc.x);
                acc.y = fmaf(vu, x[u].y, acc.y);
                acc.z = fmaf(vu, x[u].z, acc.z);
                acc.w = fmaf(vu, x[u].w, acc.w);
            }
        }
        e += 16;
    }

    // final flush + zero-fill rest of owned range (covers empty rows)
    if (sub_valid) {
        const int r_hi = min(r0 + RPS, n_nodes);
        out4[(cur_row << 4) + fl] = acc;
        for (int t = cur_row + 1; t < r_hi; ++t)
            out4[(t << 4) + fl] = make_float4(0.f, 0.f, 0.f, 0.f);
    }
}

extern "C" void kernel_launch(void* const* d_in, const int* in_sizes, int n_in,
                              void* d_out, int out_size, void* d_ws, size_t ws_size,
                              hipStream_t stream) {
    const float* seq  = (const float*)d_in[0];
    const float* vals = (const float*)d_in[1];
    const int*   rows = (const int*)d_in[2];
    const int*   cols = (const int*)d_in[3];
    float*       out  = (float*)d_out;

    const int n_edges = in_sizes[1];            // E
    const int n_nodes = out_size / 64;          // N (out is [1,N,64])

    int* row_start = (int*)d_ws;                // N+1 ints, rebuilt every call

    {
        const int threads = 256;
        const int blocks  = (n_edges + threads - 1) / threads;
        row_ptr_kernel<<<blocks, threads, 0, stream>>>(rows, row_start,
                                                       n_edges, n_nodes);
    }
    {
        const int waves  = (n_nodes + RPW - 1) / RPW;
        const int blocks = (waves + WPB - 1) / WPB;
        spmm_kernel<<<blocks, 256, 0, stream>>>(seq, vals, cols,
                                                row_start, out,
                                                n_nodes, n_edges);
    }
}

// Round 6
// 114.814 us; speedup vs baseline: 2.9288x; 1.1032x over previous
//
#include <hip/hip_runtime.h>

// COO SpMM: out[r,:] = sum_e vals[e] * seq[cols[e],:], rows sorted.
// N=50000, E=1.25M, D=64, fp32.
//
// R1: 256B gathers, atomic flush                 -> 56.6 us
// R2: deep double-buffer                         -> 66.5 us FAIL
// R3: interleaved streams + dword atomics        -> 270 us FAIL (WRITE 233MB)
// R4: float4 + ownership, scalar meta            -> 60 us
// R5: coalesced meta, 16x1KB gathers, RPS=2      -> 53 us, 3.38 TB/s, occ 29%
//     (payload model falsified; occupancy/tail starvation suspected)
// R6: RPS=1 (12500 waves -> 12.2/SIMD oversubscribed, tail-robust), gather
//     depth 8 (VGPR<=~64 for 8 waves/SIMD), predicated gathers (no waste
//     traffic), single unconditional 256B store per row (no flush logic).

#define WPB 4               // waves per 256-thread block

// row_start[t] = first edge e with rows[e] >= t, t in [0, n_nodes].
__global__ __launch_bounds__(256) void row_ptr_kernel(
    const int* __restrict__ rows, int* __restrict__ row_start,
    int n_edges, int n_nodes)
{
    const int e = blockIdx.x * blockDim.x + threadIdx.x;
    if (e >= n_edges) return;
    const int r    = rows[e];
    const int prev = (e == 0) ? -1 : rows[e - 1];
    for (int t = prev + 1; t <= r; ++t) row_start[t] = e;
    if (e == n_edges - 1)
        for (int t = r + 1; t <= n_nodes; ++t) row_start[t] = n_edges;
}

__global__ __launch_bounds__(256) void spmm_kernel(
    const float* __restrict__ seq,        // [N, 64]
    const float* __restrict__ vals,       // [E]
    const int*   __restrict__ cols,       // [E]
    const int*   __restrict__ row_start,  // [N+1]
    float*       __restrict__ out,        // [N, 64]
    int n_nodes, int n_edges)
{
    const int lane = threadIdx.x & 63;
    const int sub  = lane >> 4;           // 16-lane sub-wave id (0..3)
    const int fl   = lane & 15;           // feature quad: floats 4*fl..4*fl+3
    const int wave = blockIdx.x * WPB + (threadIdx.x >> 6);

    const int r = wave * 4 + sub;         // ONE row per sub
    if (wave * 4 >= n_nodes) return;      // wave-uniform exit
    const bool valid = (r < n_nodes);

    int e = 0, e_end = 0;
    if (valid) {
        e     = row_start[r];
        e_end = row_start[r + 1];
    }

    const float4* seq4 = (const float4*)seq;   // [N][16]
    float4 acc = make_float4(0.f, 0.f, 0.f, 0.f);

    while (__any(e < e_end)) {
        // coalesced metadata: next 16 edges of this sub (4 x 64 B segs/instr)
        int cidx = e + fl;
        cidx = (cidx < 0) ? 0 : (cidx >= n_edges ? n_edges - 1 : cidx);
        const int   c = cols[cidx];
        const float v = vals[cidx];

        // two half-chunks: 8 gathers in flight, then consume
#pragma unroll
        for (int h = 0; h < 2; ++h) {
            float4 x[8];
#pragma unroll
            for (int u = 0; u < 8; ++u) {
                const int j  = h * 8 + u;
                const int cu = __shfl(c, (sub << 4) | j);   // sub-local bcast
                if (e + j < e_end)                          // no waste traffic
                    x[u] = seq4[(cu << 4) + fl];
            }
#pragma unroll
            for (int u = 0; u < 8; ++u) {
                const int   j  = h * 8 + u;
                const float vu = __shfl(v, (sub << 4) | j);
                if (e + j < e_end) {
                    acc.x = fmaf(vu, x[u].x, acc.x);
                    acc.y = fmaf(vu, x[u].y, acc.y);
                    acc.z = fmaf(vu, x[u].z, acc.z);
                    acc.w = fmaf(vu, x[u].w, acc.w);
                }
            }
        }
        e += 16;
    }

    // exactly one 256B store per row; also zeroes empty rows
    if (valid)
        ((float4*)out)[(r << 4) + fl] = acc;
}

extern "C" void kernel_launch(void* const* d_in, const int* in_sizes, int n_in,
                              void* d_out, int out_size, void* d_ws, size_t ws_size,
                              hipStream_t stream) {
    const float* seq  = (const float*)d_in[0];
    const float* vals = (const float*)d_in[1];
    const int*   rows = (const int*)d_in[2];
    const int*   cols = (const int*)d_in[3];
    float*       out  = (float*)d_out;

    const int n_edges = in_sizes[1];            // E
    const int n_nodes = out_size / 64;          // N (out is [1,N,64])

    int* row_start = (int*)d_ws;                // N+1 ints, rebuilt every call

    {
        const int threads = 256;
        const int blocks  = (n_edges + threads - 1) / threads;
        row_ptr_kernel<<<blocks, threads, 0, stream>>>(rows, row_start,
                                                       n_edges, n_nodes);
    }
    {
        const int waves  = (n_nodes + 3) / 4;   // one row per 16-lane sub
        const int blocks = (waves + WPB - 1) / WPB;
        spmm_kernel<<<blocks, 256, 0, stream>>>(seq, vals, cols,
                                                row_start, out,
                                                n_nodes, n_edges);
    }
}

// Round 7
// 99.389 us; speedup vs baseline: 3.3833x; 1.1552x over previous
//
#include <hip/hip_runtime.h>

// COO SpMM: out[r,:] = sum_e vals[e] * seq[cols[e],:], rows sorted.
// N=50000, E=1.25M, D=64, fp32 in/out.
//
// R1: 256B gathers, atomic flush             -> 56.6 us
// R2: deep double-buffer                     -> 66.5 us FAIL
// R3: interleaved streams + dword atomics    -> 270 us FAIL
// R4: float4 + ownership, scalar meta        -> 60 us
// R5: coalesced meta, 16x1KB gathers, RPS=2  -> 53 us (3.4 TB/s, occ 29%)
// R6: RPS=1, oversubscribed, depth 8         -> ~41 us (~3.6 TB/s fetch path)
//     Fetch-path BW flattening at ~3.6 TB/s across R4-R6 -> XCD->fabric
//     random-line-read ceiling. Stop pushing BW; cut the BYTES.
// R7: gather from a bf16 copy of seq (fp32 vals + fp32 accumulation;
//     threshold 0.3825 is bf16-floor based, expected absmax ~0.01-0.06).
//     Per-XCD compulsory seq fetch 12.8->6.4 MB; row = 128 B = 1 line/edge;
//     depth-16 uint2 gathers = whole chunk in one latency round, VGPR ~60.

#define WPB 4               // waves per 256-thread block

// row_start[t] = first edge e with rows[e] >= t, t in [0, n_nodes].
__global__ __launch_bounds__(256) void row_ptr_kernel(
    const int* __restrict__ rows, int* __restrict__ row_start,
    int n_edges, int n_nodes)
{
    const int e = blockIdx.x * blockDim.x + threadIdx.x;
    if (e >= n_edges) return;
    const int r    = rows[e];
    const int prev = (e == 0) ? -1 : rows[e - 1];
    for (int t = prev + 1; t <= r; ++t) row_start[t] = e;
    if (e == n_edges - 1)
        for (int t = r + 1; t <= n_nodes; ++t) row_start[t] = n_edges;
}

// fp32 -> packed bf16 (RNE), float4 -> uint2 per thread
__global__ __launch_bounds__(256) void cvt_kernel(
    const float4* __restrict__ in, uint2* __restrict__ out, int n4)
{
    const int i = blockIdx.x * blockDim.x + threadIdx.x;
    if (i >= n4) return;
    const float4 f = in[i];
    const unsigned ux = __float_as_uint(f.x), uy = __float_as_uint(f.y);
    const unsigned uz = __float_as_uint(f.z), uw = __float_as_uint(f.w);
    const unsigned bx = (ux + 0x7FFFu + ((ux >> 16) & 1u)) >> 16;
    const unsigned by = (uy + 0x7FFFu + ((uy >> 16) & 1u)) >> 16;
    const unsigned bz = (uz + 0x7FFFu + ((uz >> 16) & 1u)) >> 16;
    const unsigned bw = (uw + 0x7FFFu + ((uw >> 16) & 1u)) >> 16;
    uint2 o;
    o.x = bx | (by << 16);
    o.y = bz | (bw << 16);
    out[i] = o;
}

__global__ __launch_bounds__(256) void spmm_kernel(
    const uint2* __restrict__ seqb,       // [N][16] packed bf16 (128 B/row)
    const float* __restrict__ vals,       // [E]
    const int*   __restrict__ cols,       // [E]
    const int*   __restrict__ row_start,  // [N+1]
    float*       __restrict__ out,        // [N, 64]
    int n_nodes, int n_edges)
{
    const int lane = threadIdx.x & 63;
    const int sub  = lane >> 4;           // 16-lane sub-wave id (0..3)
    const int fl   = lane & 15;           // feature quad: floats 4*fl..4*fl+3
    const int wave = blockIdx.x * WPB + (threadIdx.x >> 6);

    const int r = wave * 4 + sub;         // one row per sub
    if (wave * 4 >= n_nodes) return;      // wave-uniform exit
    const bool valid = (r < n_nodes);

    int e = 0, e_end = 0;
    if (valid) {
        e     = row_start[r];
        e_end = row_start[r + 1];
    }

    float4 acc = make_float4(0.f, 0.f, 0.f, 0.f);

    while (__any(e < e_end)) {
        // coalesced metadata: next 16 edges of this sub
        int cidx = e + fl;
        cidx = (cidx < 0) ? 0 : (cidx >= n_edges ? n_edges - 1 : cidx);
        const int   c = cols[cidx];
        const float v = vals[cidx];

        // whole chunk issued in one round: 16 independent 512 B gathers
        uint2 x[16];
#pragma unroll
        for (int u = 0; u < 16; ++u) {
            const int cu = __shfl(c, (sub << 4) | u);   // sub-local broadcast
            if (e + u < e_end)
                x[u] = seqb[(cu << 4) + fl];            // 8 B: 4 bf16 feats
        }
#pragma unroll
        for (int u = 0; u < 16; ++u) {
            const float vu = __shfl(v, (sub << 4) | u);
            if (e + u < e_end) {
                const float f0 = __uint_as_float(x[u].x << 16);
                const float f1 = __uint_as_float(x[u].x & 0xFFFF0000u);
                const float f2 = __uint_as_float(x[u].y << 16);
                const float f3 = __uint_as_float(x[u].y & 0xFFFF0000u);
                acc.x = fmaf(vu, f0, acc.x);
                acc.y = fmaf(vu, f1, acc.y);
                acc.z = fmaf(vu, f2, acc.z);
                acc.w = fmaf(vu, f3, acc.w);
            }
        }
        e += 16;
    }

    // exactly one 256 B store per row; also zeroes empty rows
    if (valid)
        ((float4*)out)[(r << 4) + fl] = acc;
}

extern "C" void kernel_launch(void* const* d_in, const int* in_sizes, int n_in,
                              void* d_out, int out_size, void* d_ws, size_t ws_size,
                              hipStream_t stream) {
    const float* seq  = (const float*)d_in[0];
    const float* vals = (const float*)d_in[1];
    const int*   rows = (const int*)d_in[2];
    const int*   cols = (const int*)d_in[3];
    float*       out  = (float*)d_out;

    const int n_edges = in_sizes[1];            // E
    const int n_nodes = out_size / 64;          // N (out is [1,N,64])

    // ws layout: [row_start: (N+1) ints][pad to 256][seq_bf16: N*128 B]
    int*   row_start = (int*)d_ws;
    size_t off       = (((size_t)(n_nodes + 1) * 4 + 255) / 256) * 256;
    uint2* seqb      = (uint2*)((char*)d_ws + off);

    {
        const int threads = 256;
        const int blocks  = (n_edges + threads - 1) / threads;
        row_ptr_kernel<<<blocks, threads, 0, stream>>>(rows, row_start,
                                                       n_edges, n_nodes);
    }
    {
        const int n4     = n_nodes * 16;        // float4 groups in seq
        const int blocks = (n4 + 255) / 256;
        cvt_kernel<<<blocks, 256, 0, stream>>>((const float4*)seq, seqb, n4);
    }
    {
        const int waves  = (n_nodes + 3) / 4;   // one row per 16-lane sub
        const int blocks = (waves + WPB - 1) / WPB;
        spmm_kernel<<<blocks, 256, 0, stream>>>(seqb, vals, cols,
                                                row_start, out,
                                                n_nodes, n_edges);
    }
}